// Round 3
// baseline (15441.693 us; speedup 1.0000x reference)
//
#include <hip/hip_runtime.h>

// GRU L=512, N=64, H=512, E=256, K=H+E=768. Persistent column-split kernel:
// 32 blocks x 256 threads; block b owns 16 output cols of z/r/h~; fp16 weight
// slices LDS-resident (73.7 KB, XOR-swizzled).
// Round 3: FLAGLESS dataflow sync. Exchange values (h, r*h) travel as 8-byte
// tagged units: hi32 = generation tag, lo32 = 2 packed fp16 (adjacent hidden
// cols). Producers use relaxed agent-scope 64-bit atomic stores (write-through
// to MALL); consumers spin on relaxed agent-scope 64-bit atomic loads until
// all tags match the expected step. One producer->consumer trip per phase,
// no flags, no acquire fences (L2 stays warm for ebuf/out), no __syncthreads
// in the loop (waves fully decoupled: wave w exchanges only rows 16w..16w+15).
// Exact-tag matching is safe: overwrite with tag T+1 transitively depends on
// every consumer's read of tag T. Tags re-zeroed by per-launch memset.
// Numerics: fp16 operands, f32 MFMA accum, f32 state (measured absmax 3.9e-3).

#define LSTEPS 512
#define NBATCH 64
#define HDIM   512
#define EDIM   256
#define KDIM   768
#define NBLK   32
#define TPB    256

typedef _Float16 f16x8 __attribute__((ext_vector_type(8)));
typedef float    f32x4 __attribute__((ext_vector_type(4)));
typedef unsigned long long u64;

__device__ __forceinline__ float sigm(float x){ return 1.0f/(1.0f+__expf(-x)); }
__device__ __forceinline__ float tanh_fast(float x){
  float e = __expf(2.0f*x);
  return 1.0f - 2.0f/(e + 1.0f);
}
__device__ __forceinline__ unsigned f16b(float x){
  union { _Float16 h; unsigned short u; } c; c.h = (_Float16)x; return (unsigned)c.u;
}

// Transpose+convert weights: wbuf[g][j][k] = fp16(W_g[k][j]); g in {z,r,h}.
__global__ void prep_w(const float* __restrict__ Wz, const float* __restrict__ Wr,
                       const float* __restrict__ Wh, _Float16* __restrict__ wbuf){
  int tid = blockIdx.x*256 + threadIdx.x;        // 3*512*768 = 1179648 threads
  int g   = tid / (HDIM*KDIM);
  int rem = tid - g*(HDIM*KDIM);
  int j   = rem / KDIM;
  int k   = rem - j*KDIM;
  const float* W = (g==0) ? Wz : ((g==1) ? Wr : Wh);
  wbuf[tid] = (_Float16)W[(size_t)k*HDIM + j];
}

// Gather embedding rows + convert: ebuf[t][n][k] = fp16(emb[x[t][n]][k]).
__global__ void prep_emb(const int* __restrict__ x, const float* __restrict__ emb,
                         _Float16* __restrict__ ebuf){
  int tid = blockIdx.x*256 + threadIdx.x;        // one float4 each
  int k4  = tid & 63;                            // E/4 = 64
  int tn  = tid >> 6;                            // 0..L*N-1
  int row = x[tn];
  const float4 v = *(const float4*)(emb + (size_t)row*EDIM + (k4<<2));
  union { _Float16 h[4]; uint2 u; } p;
  p.h[0] = (_Float16)v.x; p.h[1] = (_Float16)v.y;
  p.h[2] = (_Float16)v.z; p.h[3] = (_Float16)v.w;
  *(uint2*)(ebuf + (size_t)tn*EDIM + (k4<<2)) = p.u;
}

// Tagged exchange store of (rows n0..n0+3, col jcol) -> [64][256] u64 units.
// Lane pair (2q,2q+1) covers cols (j,j+1): shfl_xor repack -> even lane
// stores rows n0..n0+1, odd lane rows n0+2..n0+3, each as one 8B unit
// (hi32 = tag, lo32 = fp16 pair). Relaxed agent atomics = write-through.
__device__ __forceinline__ void store_tagged(u64* buf, int jc2u, int n0, int lane,
                                             unsigned tag,
                                             float v0, float v1, float v2, float v3){
  unsigned p01 = f16b(v0) | (f16b(v1) << 16);
  unsigned p23 = f16b(v2) | (f16b(v3) << 16);
  unsigned q01 = __shfl_xor(p01, 1, 64);
  unsigned q23 = __shfl_xor(p23, 1, 64);
  unsigned w0, w1; int r0;
  if (lane & 1){                       // own col = j+1 (high half of pair)
    w0 = (q23 & 0xffffu) | (p23 << 16);
    w1 = (q23 >> 16)     | (p23 & 0xffff0000u);
    r0 = n0 + 2;
  } else {                             // own col = j (low half)
    w0 = (p01 & 0xffffu) | (q01 << 16);
    w1 = (p01 >> 16)     | (q01 & 0xffff0000u);
    r0 = n0;
  }
  u64 t64 = ((u64)tag) << 32;
  __hip_atomic_store(buf + (size_t)r0*256 + jc2u,     t64 | (u64)w0,
                     __ATOMIC_RELAXED, __HIP_MEMORY_SCOPE_AGENT);
  __hip_atomic_store(buf + (size_t)(r0+1)*256 + jc2u, t64 | (u64)w1,
                     __ATOMIC_RELAXED, __HIP_MEMORY_SCOPE_AGENT);
}

__global__ __launch_bounds__(TPB, 1) void gru_persist(
    const _Float16* __restrict__ wbuf,   // [3][512][768] fp16 (col-major per gate)
    const _Float16* __restrict__ ebuf,   // [L][64][256] fp16
    const float* __restrict__ bz, const float* __restrict__ br, const float* __restrict__ bh,
    u64* __restrict__ hx,                // [64][256] tagged h units
    u64* __restrict__ rhx,               // [64][256] tagged r*h units
    float* __restrict__ out)             // [L][64][512] f32
{
  __shared__ char wlds[3*16*1536];       // 73728 B: [gate][col16][768 fp16]
  const int jbase = blockIdx.x * 16;

  // Stage weight slices -> LDS, XOR-swizzled by col to spread banks.
  for (int cidx = threadIdx.x; cidx < 3*16*96; cidx += TPB){
    int g   = cidx / (16*96);
    int rem = cidx - g*(16*96);
    int col = rem / 96;
    int kch = rem - col*96;              // 16B chunk index along K
    const uint4 v = *(const uint4*)(wbuf + ((size_t)(g*HDIM + jbase + col))*KDIM + kch*8);
    int off = (((g*16 + col)*1536) + kch*16) ^ ((col & 7) << 4);
    *(uint4*)(wlds + off) = v;
  }
  __syncthreads();

  const int lane = threadIdx.x & 63;
  const int wave = threadIdx.x >> 6;     // M-tile: rows 16*wave..16*wave+15
  const int c15  = lane & 15;
  const int kgrp = lane >> 4;
  const int jcol = jbase + c15;
  const int jc2u = jcol >> 1;            // u64 unit index of own col pair
  const int arow = wave*16 + c15;        // A-fragment row (batch)
  const int n0   = wave*16 + kgrp*4;     // C/D row base (batch)
  const int swz  = (c15 & 7) << 4;
  const int linz = ((      c15)*1536) + kgrp*16;
  const int linr = ((16  + c15)*1536) + kgrp*16;
  const int linh = ((32  + c15)*1536) + kgrp*16;
  const float bzj = bz[jcol];
  const float brj = br[jcol];
  const float bhj = bh[jcol];
  const u64* hrow  = hx  + (size_t)arow*256 + kgrp*4;   // + kc*16 + i
  const u64* rhrow = rhx + (size_t)arow*256 + kgrp*4;
  float hreg[4] = {0.f, 0.f, 0.f, 0.f};  // private f32 hidden state

  u64 q[64];                              // tagged-load bank (128 VGPRs)

#define LOADQ(BASE) do {                                                      \
    _Pragma("unroll")                                                         \
    for (int kc = 0; kc < 16; ++kc){                                          \
      _Pragma("unroll")                                                       \
      for (int i = 0; i < 4; ++i)                                             \
        q[kc*4+i] = __hip_atomic_load((BASE) + kc*16 + i,                     \
                      __ATOMIC_RELAXED, __HIP_MEMORY_SCOPE_AGENT);            \
    }                                                                         \
  } while (0)

  for (int t = 0; t < LSTEPS; ++t){
    const _Float16* ae = ebuf + ((size_t)t*NBATCH + arow)*EDIM + kgrp*8;
    const unsigned texp = (unsigned)t;        // tag expected on h this step
    const unsigned twr  = (unsigned)(t + 1);  // tag written this step

    // ---------------- phase 1: z, r ----------------
    LOADQ(hrow);                           // tagged h loads in flight
    f32x4 accz = {0.f,0.f,0.f,0.f};
    f32x4 accr = {0.f,0.f,0.f,0.f};
    #pragma unroll
    for (int kc = 0; kc < 8; ++kc){        // e-part overlaps the load latency
      f16x8 a   = *(const f16x8*)(ae + kc*32);
      f16x8 bzv = *(const f16x8*)(wlds + ((linz + (16+kc)*64) ^ swz));
      f16x8 brv = *(const f16x8*)(wlds + ((linr + (16+kc)*64) ^ swz));
      accz = __builtin_amdgcn_mfma_f32_16x16x32_f16(a, bzv, accz, 0, 0, 0);
      accr = __builtin_amdgcn_mfma_f32_16x16x32_f16(a, brv, accr, 0, 0, 0);
    }
    for (;;){
      unsigned err = 0;
      #pragma unroll
      for (int i = 0; i < 64; ++i) err |= ((unsigned)(q[i] >> 32)) ^ texp;
      if (!__any(err != 0)) break;
      LOADQ(hrow);
    }
    #pragma unroll
    for (int kc = 0; kc < 16; ++kc){
      union { unsigned u[4]; f16x8 v; } a;
      #pragma unroll
      for (int i = 0; i < 4; ++i) a.u[i] = (unsigned)q[kc*4+i];
      f16x8 bzv = *(const f16x8*)(wlds + ((linz + kc*64) ^ swz));
      f16x8 brv = *(const f16x8*)(wlds + ((linr + kc*64) ^ swz));
      accz = __builtin_amdgcn_mfma_f32_16x16x32_f16(a.v, bzv, accz, 0, 0, 0);
      accr = __builtin_amdgcn_mfma_f32_16x16x32_f16(a.v, brv, accr, 0, 0, 0);
    }
    float zreg[4], rh[4];
    #pragma unroll
    for (int i = 0; i < 4; ++i){
      zreg[i] = sigm(accz[i] + bzj);
      rh[i]   = sigm(accr[i] + brj) * hreg[i];
    }
    store_tagged(rhx, jc2u, n0, lane, twr, rh[0], rh[1], rh[2], rh[3]);

    // ---------------- phase 2: h~, h_new ----------------
    LOADQ(rhrow);                          // tagged r*h loads in flight
    f32x4 acch = {0.f,0.f,0.f,0.f};
    #pragma unroll
    for (int kc = 0; kc < 8; ++kc){        // e-part overlaps
      f16x8 a   = *(const f16x8*)(ae + kc*32);
      f16x8 bhv = *(const f16x8*)(wlds + ((linh + (16+kc)*64) ^ swz));
      acch = __builtin_amdgcn_mfma_f32_16x16x32_f16(a, bhv, acch, 0, 0, 0);
    }
    for (;;){
      unsigned err = 0;
      #pragma unroll
      for (int i = 0; i < 64; ++i) err |= ((unsigned)(q[i] >> 32)) ^ twr;
      if (!__any(err != 0)) break;
      LOADQ(rhrow);
    }
    #pragma unroll
    for (int kc = 0; kc < 16; ++kc){
      union { unsigned u[4]; f16x8 v; } a;
      #pragma unroll
      for (int i = 0; i < 4; ++i) a.u[i] = (unsigned)q[kc*4+i];
      f16x8 bhv = *(const f16x8*)(wlds + ((linh + kc*64) ^ swz));
      acch = __builtin_amdgcn_mfma_f32_16x16x32_f16(a.v, bhv, acch, 0, 0, 0);
    }
    #pragma unroll
    for (int i = 0; i < 4; ++i){
      float ht = tanh_fast(acch[i] + bhj);
      float hn = hreg[i] + zreg[i]*(ht - hreg[i]);   // (1-z)h + z*h~
      hreg[i] = hn;
      out[((size_t)t*NBATCH + (n0+i))*HDIM + jcol] = hn;
    }
    store_tagged(hx, jc2u, n0, lane, twr, hreg[0], hreg[1], hreg[2], hreg[3]);
  }
#undef LOADQ
}

extern "C" void kernel_launch(void* const* d_in, const int* in_sizes, int n_in,
                              void* d_out, int out_size, void* d_ws, size_t ws_size,
                              hipStream_t stream) {
  const int*   x   = (const int*)  d_in[0];
  const float* emb = (const float*)d_in[1];
  const float* Wz  = (const float*)d_in[2];
  const float* bz  = (const float*)d_in[3];
  const float* Wr  = (const float*)d_in[4];
  const float* br  = (const float*)d_in[5];
  const float* Wh  = (const float*)d_in[6];
  const float* bh  = (const float*)d_in[7];
  float* out = (float*)d_out;
  char*  ws  = (char*)d_ws;

  size_t off = 0;
  u64* hx  = (u64*)(ws + off); off += (size_t)NBATCH*(HDIM/2)*8;   // 131072
  u64* rhx = (u64*)(ws + off); off += (size_t)NBATCH*(HDIM/2)*8;   // 131072
  size_t zero_bytes = off;               // tags must start at 0 every launch
  _Float16* wbuf = (_Float16*)(ws + off); off += (size_t)3*HDIM*KDIM*2;        // 2359296
  _Float16* ebuf = (_Float16*)(ws + off); off += (size_t)LSTEPS*NBATCH*EDIM*2; // 16777216

  hipMemsetAsync(ws, 0, zero_bytes, stream);

  prep_w  <<<(3*HDIM*KDIM)/256,          256, 0, stream>>>(Wz, Wr, Wh, wbuf);
  prep_emb<<<(LSTEPS*NBATCH*EDIM/4)/256, 256, 0, stream>>>(x, emb, ebuf);
  gru_persist<<<NBLK, TPB, 0, stream>>>(wbuf, ebuf, bz, br, bh, hx, rhx, out);
}

// Round 4
// 5412.666 us; speedup vs baseline: 2.8529x; 2.8529x over previous
//
#include <hip/hip_runtime.h>

// GRU L=512, N=64, H=512, E=256, K=H+E=768. Persistent column-split kernel:
// 32 blocks x 256 threads; block b owns 16 output cols of z/r/h~; fp16 weight
// slices LDS-resident (73.7 KB, XOR-swizzled).
// Round 4: per-WAVE dataflow sync, no fences, poll/payload decoupled.
//  - wave w of block b exchanges only batch rows [16w,16w+16): flags are
//    hfl[w][b], rhfl[w][b]; consumers poll only their 32-row-group flags
//    (one 4B agent atomic load per lane per poll iter).
//  - exchange data: relaxed agent-scope atomics (write-through past L2);
//    stores drained by s_waitcnt vmcnt(0) before the flag store; loads done
//    ONCE per phase as 32 pipelined u64 atomic loads per lane. The vmcnt(0)
//    also drains the wave's exchange LOADS, which makes single-buffering
//    race-free: gen T+1 stores transitively follow all gen-T reads.
//  - no acquire fences, no __syncthreads in the loop: L2 stays warm for
//    ebuf/out; only exchange traffic goes through MALL.
//  - step schedule: r e-part early; wait h; r h-part; store rh+flag; z matmul
//    (reuses h frags in regs) + h~ e-part cover the rh round-trip; wait rh;
//    h~ h-part; epilogue; store h+flag.
// Numerics: fp16 operands, f32 MFMA accum, f32 state (measured absmax 3.9e-3).

#define LSTEPS 512
#define NBATCH 64
#define HDIM   512
#define EDIM   256
#define KDIM   768
#define NBLK   32
#define TPB    256

typedef _Float16 f16x8 __attribute__((ext_vector_type(8)));
typedef float    f32x4 __attribute__((ext_vector_type(4)));
typedef unsigned long long u64;

__device__ __forceinline__ float sigm(float x){ return 1.0f/(1.0f+__expf(-x)); }
__device__ __forceinline__ float tanh_fast(float x){
  float e = __expf(2.0f*x);
  return 1.0f - 2.0f/(e + 1.0f);
}
__device__ __forceinline__ unsigned f16b(float x){
  union { _Float16 h; unsigned short u; } c; c.h = (_Float16)x; return (unsigned)c.u;
}

// Transpose+convert weights: wbuf[g][j][k] = fp16(W_g[k][j]); g in {z,r,h}.
__global__ void prep_w(const float* __restrict__ Wz, const float* __restrict__ Wr,
                       const float* __restrict__ Wh, _Float16* __restrict__ wbuf){
  int tid = blockIdx.x*256 + threadIdx.x;        // 3*512*768 = 1179648 threads
  int g   = tid / (HDIM*KDIM);
  int rem = tid - g*(HDIM*KDIM);
  int j   = rem / KDIM;
  int k   = rem - j*KDIM;
  const float* W = (g==0) ? Wz : ((g==1) ? Wr : Wh);
  wbuf[tid] = (_Float16)W[(size_t)k*HDIM + j];
}

// Gather embedding rows + convert: ebuf[t][n][k] = fp16(emb[x[t][n]][k]).
__global__ void prep_emb(const int* __restrict__ x, const float* __restrict__ emb,
                         _Float16* __restrict__ ebuf){
  int tid = blockIdx.x*256 + threadIdx.x;        // one float4 each
  int k4  = tid & 63;                            // E/4 = 64
  int tn  = tid >> 6;                            // 0..L*N-1
  int row = x[tn];
  const float4 v = *(const float4*)(emb + (size_t)row*EDIM + (k4<<2));
  union { _Float16 h[4]; uint2 u; } p;
  p.h[0] = (_Float16)v.x; p.h[1] = (_Float16)v.y;
  p.h[2] = (_Float16)v.z; p.h[3] = (_Float16)v.w;
  *(uint2*)(ebuf + (size_t)tn*EDIM + (k4<<2)) = p.u;
}

// Exchange store of (rows n0..n0+3, col jcol) as write-through 4B atomics.
// Lane pair (2q,2q+1) covers cols (j,j+1): shfl_xor repack -> even lane
// stores rows n0..n0+1, odd lane rows n0+2..n0+3, each one aligned dword.
__device__ __forceinline__ void store_x(_Float16* buf, int jc2, int n0, int lane,
                                        float v0, float v1, float v2, float v3){
  unsigned p01 = f16b(v0) | (f16b(v1) << 16);
  unsigned p23 = f16b(v2) | (f16b(v3) << 16);
  unsigned q01 = __shfl_xor(p01, 1, 64);
  unsigned q23 = __shfl_xor(p23, 1, 64);
  unsigned w0, w1; int r0;
  if (lane & 1){                       // own col = j+1 (high half of pair)
    w0 = (q23 & 0xffffu) | (p23 << 16);
    w1 = (q23 >> 16)     | (p23 & 0xffff0000u);
    r0 = n0 + 2;
  } else {                             // own col = j (low half)
    w0 = (p01 & 0xffffu) | (q01 << 16);
    w1 = (p01 >> 16)     | (q01 & 0xffff0000u);
    r0 = n0;
  }
  __hip_atomic_store((unsigned*)(buf + (size_t)r0*HDIM + jc2),     w0,
                     __ATOMIC_RELAXED, __HIP_MEMORY_SCOPE_AGENT);
  __hip_atomic_store((unsigned*)(buf + (size_t)(r0+1)*HDIM + jc2), w1,
                     __ATOMIC_RELAXED, __HIP_MEMORY_SCOPE_AGENT);
}

// Poll 32 row-group flags until all >= target. One agent atomic load/lane.
__device__ __forceinline__ void waitfl(unsigned* fl, unsigned target){
  const int l31 = threadIdx.x & 31;
  for (;;){
    unsigned v = __hip_atomic_load(&fl[l31], __ATOMIC_RELAXED, __HIP_MEMORY_SCOPE_AGENT);
    if (__all(v >= target)) break;
  }
}

__global__ __launch_bounds__(TPB, 1) void gru_persist(
    const _Float16* __restrict__ wbuf,   // [3][512][768] fp16 (col-major per gate)
    const _Float16* __restrict__ ebuf,   // [L][64][256] fp16
    const float* __restrict__ bz, const float* __restrict__ br, const float* __restrict__ bh,
    _Float16* __restrict__ hx,           // [64][512] fp16 exchange (h)
    _Float16* __restrict__ rhx,          // [64][512] fp16 exchange (r*h)
    unsigned* __restrict__ hfl,          // [4][32] h flags (wave-row-group x block)
    unsigned* __restrict__ rhfl,         // [4][32] rh flags
    float* __restrict__ out)             // [L][64][512] f32
{
  __shared__ char wlds[3*16*1536];       // 73728 B: [gate][col16][768 fp16]
  const int jbase = blockIdx.x * 16;

  // Stage weight slices -> LDS, XOR-swizzled by col to spread banks.
  for (int cidx = threadIdx.x; cidx < 3*16*96; cidx += TPB){
    int g   = cidx / (16*96);
    int rem = cidx - g*(16*96);
    int col = rem / 96;
    int kch = rem - col*96;              // 16B chunk index along K
    const uint4 v = *(const uint4*)(wbuf + ((size_t)(g*HDIM + jbase + col))*KDIM + kch*8);
    int off = (((g*16 + col)*1536) + kch*16) ^ ((col & 7) << 4);
    *(uint4*)(wlds + off) = v;
  }
  __syncthreads();                       // only barrier; loop below is per-wave

  const int lane = threadIdx.x & 63;
  const int wave = threadIdx.x >> 6;     // M-tile: rows 16*wave..16*wave+15
  const int c15  = lane & 15;
  const int kgrp = lane >> 4;
  const int jcol = jbase + c15;
  const int jc2  = jcol & ~1;
  const int arow = wave*16 + c15;        // A-fragment row (batch)
  const int n0   = wave*16 + kgrp*4;     // C/D row base (batch)
  const int swz  = (c15 & 7) << 4;
  const int linz = ((      c15)*1536) + kgrp*16;
  const int linr = ((16  + c15)*1536) + kgrp*16;
  const int linh = ((32  + c15)*1536) + kgrp*16;
  const float bzj = bz[jcol];
  const float brj = br[jcol];
  const float bhj = bh[jcol];
  unsigned* myhfl  = hfl  + wave*32;     // this wave's row-group flag row
  unsigned* myrhfl = rhfl + wave*32;
  const u64* hrow  = (const u64*)hx  + (size_t)arow*128 + kgrp*2;  // + kc*8 (+1)
  const u64* rhrow = (const u64*)rhx + (size_t)arow*128 + kgrp*2;
  float hreg[4] = {0.f, 0.f, 0.f, 0.f};  // private f32 hidden state

  u64 q[32];                              // one row-panel of A fragments

#define LOADX(BASE) do {                                                      \
    _Pragma("unroll")                                                         \
    for (int kc = 0; kc < 16; ++kc){                                          \
      q[2*kc]   = __hip_atomic_load((BASE) + kc*8,     __ATOMIC_RELAXED,      \
                                    __HIP_MEMORY_SCOPE_AGENT);                \
      q[2*kc+1] = __hip_atomic_load((BASE) + kc*8 + 1, __ATOMIC_RELAXED,      \
                                    __HIP_MEMORY_SCOPE_AGENT);                \
    }                                                                         \
  } while (0)

#define AFRAG(KC) ({ union { u64 d[2]; f16x8 v; } _a;                         \
                     _a.d[0] = q[2*(KC)]; _a.d[1] = q[2*(KC)+1]; _a.v; })

  for (int t = 0; t < LSTEPS; ++t){
    const _Float16* ae = ebuf + ((size_t)t*NBATCH + arow)*EDIM + kgrp*8;
    const unsigned tago = (unsigned)t;        // h generation consumed
    const unsigned tagn = (unsigned)(t + 1);  // generation produced

    // ---- r gate: e-part first (independent), then wait h, h-part.
    f32x4 accr = {0.f,0.f,0.f,0.f};
    #pragma unroll
    for (int kc = 0; kc < 8; ++kc){
      f16x8 a   = *(const f16x8*)(ae + kc*32);
      f16x8 brv = *(const f16x8*)(wlds + ((linr + (16+kc)*64) ^ swz));
      accr = __builtin_amdgcn_mfma_f32_16x16x32_f16(a, brv, accr, 0, 0, 0);
    }
    waitfl(myhfl, tago);                 // t=0: flags start 0, passes; hx=0
    LOADX(hrow);
    #pragma unroll
    for (int kc = 0; kc < 16; ++kc){
      f16x8 brv = *(const f16x8*)(wlds + ((linr + kc*64) ^ swz));
      accr = __builtin_amdgcn_mfma_f32_16x16x32_f16(AFRAG(kc), brv, accr, 0, 0, 0);
    }
    float rh[4];
    #pragma unroll
    for (int i = 0; i < 4; ++i)
      rh[i] = sigm(accr[i] + brj) * hreg[i];
    store_x(rhx, jc2, n0, lane, rh[0], rh[1], rh[2], rh[3]);
    asm volatile("s_waitcnt vmcnt(0)" ::: "memory");   // rh stores + h loads drained
    if (lane == 0)
      __hip_atomic_store(&myrhfl[blockIdx.x], tagn,
                         __ATOMIC_RELAXED, __HIP_MEMORY_SCOPE_AGENT);

    // ---- cover the rh round-trip: z matmul (h frags still in regs) + h~ e-part.
    f32x4 accz = {0.f,0.f,0.f,0.f};
    f32x4 acch = {0.f,0.f,0.f,0.f};
    #pragma unroll
    for (int kc = 0; kc < 16; ++kc){
      f16x8 bzv = *(const f16x8*)(wlds + ((linz + kc*64) ^ swz));
      accz = __builtin_amdgcn_mfma_f32_16x16x32_f16(AFRAG(kc), bzv, accz, 0, 0, 0);
    }
    #pragma unroll
    for (int kc = 0; kc < 8; ++kc){
      f16x8 a   = *(const f16x8*)(ae + kc*32);
      f16x8 bzv = *(const f16x8*)(wlds + ((linz + (16+kc)*64) ^ swz));
      f16x8 bhv = *(const f16x8*)(wlds + ((linh + (16+kc)*64) ^ swz));
      accz = __builtin_amdgcn_mfma_f32_16x16x32_f16(a, bzv, accz, 0, 0, 0);
      acch = __builtin_amdgcn_mfma_f32_16x16x32_f16(a, bhv, acch, 0, 0, 0);
    }
    float zreg[4];
    #pragma unroll
    for (int i = 0; i < 4; ++i) zreg[i] = sigm(accz[i] + bzj);

    // ---- h~: wait rh, h-part, epilogue, publish h.
    waitfl(myrhfl, tagn);
    LOADX(rhrow);
    #pragma unroll
    for (int kc = 0; kc < 16; ++kc){
      f16x8 bhv = *(const f16x8*)(wlds + ((linh + kc*64) ^ swz));
      acch = __builtin_amdgcn_mfma_f32_16x16x32_f16(AFRAG(kc), bhv, acch, 0, 0, 0);
    }
    #pragma unroll
    for (int i = 0; i < 4; ++i){
      float ht = tanh_fast(acch[i] + bhj);
      float hn = hreg[i] + zreg[i]*(ht - hreg[i]);   // (1-z)h + z*h~
      hreg[i] = hn;
      out[((size_t)t*NBATCH + (n0+i))*HDIM + jcol] = hn;
    }
    store_x(hx, jc2, n0, lane, hreg[0], hreg[1], hreg[2], hreg[3]);
    asm volatile("s_waitcnt vmcnt(0)" ::: "memory");   // h stores + rh loads drained
    if (lane == 0)
      __hip_atomic_store(&myhfl[blockIdx.x], tagn,
                         __ATOMIC_RELAXED, __HIP_MEMORY_SCOPE_AGENT);
  }
#undef LOADX
#undef AFRAG
}

extern "C" void kernel_launch(void* const* d_in, const int* in_sizes, int n_in,
                              void* d_out, int out_size, void* d_ws, size_t ws_size,
                              hipStream_t stream) {
  const int*   x   = (const int*)  d_in[0];
  const float* emb = (const float*)d_in[1];
  const float* Wz  = (const float*)d_in[2];
  const float* bz  = (const float*)d_in[3];
  const float* Wr  = (const float*)d_in[4];
  const float* br  = (const float*)d_in[5];
  const float* Wh  = (const float*)d_in[6];
  const float* bh  = (const float*)d_in[7];
  float* out = (float*)d_out;
  char*  ws  = (char*)d_ws;

  size_t off = 0;
  unsigned* hfl  = (unsigned*)(ws + off); off += 4*32*4;                    // 512
  unsigned* rhfl = (unsigned*)(ws + off); off += 4*32*4;                    // 512
  _Float16* hx   = (_Float16*)(ws + off); off += (size_t)NBATCH*HDIM*2;     // 65536
  size_t zero_bytes = off;               // flags + hx must start at 0
  _Float16* rhx  = (_Float16*)(ws + off); off += (size_t)NBATCH*HDIM*2;     // 65536
  _Float16* wbuf = (_Float16*)(ws + off); off += (size_t)3*HDIM*KDIM*2;     // 2359296
  _Float16* ebuf = (_Float16*)(ws + off); off += (size_t)LSTEPS*NBATCH*EDIM*2; // 16777216

  hipMemsetAsync(ws, 0, zero_bytes, stream);

  prep_w  <<<(3*HDIM*KDIM)/256,          256, 0, stream>>>(Wz, Wr, Wh, wbuf);
  prep_emb<<<(LSTEPS*NBATCH*EDIM/4)/256, 256, 0, stream>>>(x, emb, ebuf);
  gru_persist<<<NBLK, TPB, 0, stream>>>(wbuf, ebuf, bz, br, bh,
                                        hx, rhx, hfl, rhfl, out);
}